// Round 1
// baseline (6310.876 us; speedup 1.0000x reference)
//
#include <hip/hip_runtime.h>
#include <utility>

// ---------------- constants ----------------
#define BATCH   2
#define NT      16385          // tokens incl cls
#define NP      16640          // nystrom-padded length (65*256)
#define PADT    255            // front padding
#define LM      256            // landmarks
#define LAVG    65             // tokens averaged per landmark
#define NHEADS  8
#define DH      64
#define DIM     512
#define INDIM   1536
#define BH      (BATCH*NHEADS)
#define LNEPS   1e-5f
#define QSCALE  0.125f
#define KSPLIT  20
#define KCHUNK  832            // NP / KSPLIT, divisible by 32

// ---------------- tiny kernels ----------------
__global__ void k_set_cls(const float* __restrict__ cls, float* __restrict__ h) {
    int i = blockIdx.x * 256 + threadIdx.x;
    if (i < BATCH * DIM) {
        int b = i / DIM, c = i % DIM;
        h[(size_t)b * NT * DIM + c] = cls[c];
    }
}

__global__ void k_copy_cls(const float* __restrict__ src, float* __restrict__ dst) {
    int i = blockIdx.x * 256 + threadIdx.x;
    if (i < BATCH * DIM) {
        int b = i / DIM, c = i % DIM;
        dst[(size_t)b * NT * DIM + c] = src[(size_t)b * NT * DIM + c];
    }
}

__global__ void k_zero_pads(float* __restrict__ q, float* __restrict__ k, float* __restrict__ v) {
    int idx = blockIdx.x * 256 + threadIdx.x;
    const int per = PADT * DH;               // pad region per bh (contiguous rows 0..254)
    if (idx < BH * per) {
        int bh = idx / per, rest = idx % per;
        size_t off = (size_t)bh * NP * DH + rest;
        q[off] = 0.f; k[off] = 0.f; v[off] = 0.f;
    }
}

// ---------------- big GEMMs (64x64 tile, BK=16, 4x4/thread) ----------------
__global__ __launch_bounds__(256) void k_gemm_w1(
        const float* __restrict__ A, const float* __restrict__ W,
        const float* __restrict__ bias, float* __restrict__ hout) {
    const int K = INDIM, N = DIM;
    __shared__ float As[16][64];
    __shared__ float Bs[16][64];
    int tid = threadIdx.x;
    int n0 = blockIdx.x * 64, m0 = blockIdx.y * 64;
    int tx = tid & 15, ty = tid >> 4;
    int ar = tid >> 2, ac = (tid & 3) * 4;
    int br = tid >> 4, bc = (tid & 15) * 4;
    float acc[4][4] = {};
    for (int k0 = 0; k0 < K; k0 += 16) {
        float4 va = *(const float4*)(A + (size_t)(m0 + ar) * K + k0 + ac);
        As[ac + 0][ar] = va.x; As[ac + 1][ar] = va.y; As[ac + 2][ar] = va.z; As[ac + 3][ar] = va.w;
        float4 vb = *(const float4*)(W + (size_t)(k0 + br) * N + n0 + bc);
        *(float4*)&Bs[br][bc] = vb;
        __syncthreads();
#pragma unroll
        for (int kk = 0; kk < 16; kk++) {
            float a_[4], b_[4];
#pragma unroll
            for (int i = 0; i < 4; i++) a_[i] = As[kk][ty * 4 + i];
#pragma unroll
            for (int j = 0; j < 4; j++) b_[j] = Bs[kk][tx * 4 + j];
#pragma unroll
            for (int i = 0; i < 4; i++)
#pragma unroll
                for (int j = 0; j < 4; j++) acc[i][j] += a_[i] * b_[j];
        }
        __syncthreads();
    }
#pragma unroll
    for (int i = 0; i < 4; i++) {
        int r = m0 + ty * 4 + i;            // r in [0, 32768)
        int b = r >> 14;
        size_t orow = (size_t)r + b + 1;    // h row = b*NT + 1 + (r - b*16384)
#pragma unroll
        for (int j = 0; j < 4; j++) {
            int c = n0 + tx * 4 + j;
            float vv = acc[i][j] + bias[c];
            hout[orow * DIM + c] = fmaxf(vv, 0.f);
        }
    }
}

__global__ __launch_bounds__(256) void k_gemm_qkv(
        const float* __restrict__ A, const float* __restrict__ W,
        float* __restrict__ q, float* __restrict__ k, float* __restrict__ v) {
    const int M = BATCH * NT, K = DIM, N = 3 * DIM;
    __shared__ float As[16][64];
    __shared__ float Bs[16][64];
    int tid = threadIdx.x;
    int n0 = blockIdx.x * 64, m0 = blockIdx.y * 64;
    int tx = tid & 15, ty = tid >> 4;
    int ar = tid >> 2, ac = (tid & 3) * 4;
    int br = tid >> 4, bc = (tid & 15) * 4;
    float acc[4][4] = {};
    for (int k0 = 0; k0 < K; k0 += 16) {
        int gr = m0 + ar;
        float4 va = make_float4(0.f, 0.f, 0.f, 0.f);
        if (gr < M) va = *(const float4*)(A + (size_t)gr * K + k0 + ac);
        As[ac + 0][ar] = va.x; As[ac + 1][ar] = va.y; As[ac + 2][ar] = va.z; As[ac + 3][ar] = va.w;
        float4 vb = *(const float4*)(W + (size_t)(k0 + br) * N + n0 + bc);
        *(float4*)&Bs[br][bc] = vb;
        __syncthreads();
#pragma unroll
        for (int kk = 0; kk < 16; kk++) {
            float a_[4], b_[4];
#pragma unroll
            for (int i = 0; i < 4; i++) a_[i] = As[kk][ty * 4 + i];
#pragma unroll
            for (int j = 0; j < 4; j++) b_[j] = Bs[kk][tx * 4 + j];
#pragma unroll
            for (int i = 0; i < 4; i++)
#pragma unroll
                for (int j = 0; j < 4; j++) acc[i][j] += a_[i] * b_[j];
        }
        __syncthreads();
    }
#pragma unroll
    for (int i = 0; i < 4; i++) {
        int r = m0 + ty * 4 + i;
        if (r >= M) continue;
        int b = r / NT, tok = r % NT;
        size_t t = (size_t)tok + PADT;
#pragma unroll
        for (int j = 0; j < 4; j++) {
            int c = n0 + tx * 4 + j;
            int sel = c >> 9;
            int hh = (c >> 6) & 7;
            int d = c & 63;
            float vv = acc[i][j];
            float* dst = (sel == 0) ? q : (sel == 1) ? k : v;
            if (sel == 0) vv *= QSCALE;
            dst[((size_t)(b * NHEADS + hh) * NP + t) * DH + d] = vv;
        }
    }
}

__global__ __launch_bounds__(256) void k_gemm_outproj(
        const float* __restrict__ A, const float* __restrict__ W,
        const float* __restrict__ bias, float* __restrict__ hio) {
    const int M = BATCH * NT, K = DIM, N = DIM;
    __shared__ float As[16][64];
    __shared__ float Bs[16][64];
    int tid = threadIdx.x;
    int n0 = blockIdx.x * 64, m0 = blockIdx.y * 64;
    int tx = tid & 15, ty = tid >> 4;
    int ar = tid >> 2, ac = (tid & 3) * 4;
    int br = tid >> 4, bc = (tid & 15) * 4;
    float acc[4][4] = {};
    for (int k0 = 0; k0 < K; k0 += 16) {
        int gr = m0 + ar;
        float4 va = make_float4(0.f, 0.f, 0.f, 0.f);
        if (gr < M) va = *(const float4*)(A + (size_t)gr * K + k0 + ac);
        As[ac + 0][ar] = va.x; As[ac + 1][ar] = va.y; As[ac + 2][ar] = va.z; As[ac + 3][ar] = va.w;
        float4 vb = *(const float4*)(W + (size_t)(k0 + br) * N + n0 + bc);
        *(float4*)&Bs[br][bc] = vb;
        __syncthreads();
#pragma unroll
        for (int kk = 0; kk < 16; kk++) {
            float a_[4], b_[4];
#pragma unroll
            for (int i = 0; i < 4; i++) a_[i] = As[kk][ty * 4 + i];
#pragma unroll
            for (int j = 0; j < 4; j++) b_[j] = Bs[kk][tx * 4 + j];
#pragma unroll
            for (int i = 0; i < 4; i++)
#pragma unroll
                for (int j = 0; j < 4; j++) acc[i][j] += a_[i] * b_[j];
        }
        __syncthreads();
    }
#pragma unroll
    for (int i = 0; i < 4; i++) {
        int r = m0 + ty * 4 + i;
        if (r >= M) continue;
#pragma unroll
        for (int j = 0; j < 4; j++) {
            int c = n0 + tx * 4 + j;
            hio[(size_t)r * DIM + c] += acc[i][j] + bias[c];
        }
    }
}

// ---------------- layernorm ----------------
__global__ __launch_bounds__(256) void k_ln(
        const float* __restrict__ x, const float* __restrict__ g,
        const float* __restrict__ bb, float* __restrict__ y) {
    size_t row = blockIdx.x;
    const float* xr = x + row * DIM;
    float* yr = y + row * DIM;
    int tid = threadIdx.x;
    __shared__ float red[256];
    float v0 = xr[tid], v1 = xr[tid + 256];
    red[tid] = v0 + v1;
    __syncthreads();
    for (int o = 128; o > 0; o >>= 1) { if (tid < o) red[tid] += red[tid + o]; __syncthreads(); }
    float mu = red[0] * (1.0f / DIM);
    __syncthreads();
    float d0 = v0 - mu, d1 = v1 - mu;
    red[tid] = d0 * d0 + d1 * d1;
    __syncthreads();
    for (int o = 128; o > 0; o >>= 1) { if (tid < o) red[tid] += red[tid + o]; __syncthreads(); }
    float rs = rsqrtf(red[0] * (1.0f / DIM) + LNEPS);
    yr[tid] = d0 * rs * g[tid] + bb[tid];
    yr[tid + 256] = d1 * rs * g[tid + 256] + bb[tid + 256];
}

// ---------------- landmarks (mean over LAVG consecutive rows) ----------------
__global__ void k_landmark(const float* __restrict__ x, float* __restrict__ xl) {
    int bh = blockIdx.z, i = blockIdx.y, d = threadIdx.x;   // block 64
    const float* p = x + ((size_t)bh * NP + (size_t)i * LAVG) * DH + d;
    float s = 0.f;
    for (int j = 0; j < LAVG; j++) s += p[(size_t)j * DH];
    xl[((size_t)bh * LM + i) * DH + d] = s * (1.0f / LAVG);
}

// ---------------- scores: C[bh,r,c] = A[bh,r,:]·B[bh,c,:]  (K=64) ----------------
__global__ __launch_bounds__(256) void k_scores(
        const float* __restrict__ A, const float* __restrict__ Bm,
        float* __restrict__ C, int Mrows, int Ncols) {
    int bh = blockIdx.z;
    int c0 = blockIdx.x * 64, r0 = blockIdx.y * 64;
    __shared__ float As[64][DH + 1];
    __shared__ float Bs[64][DH + 1];
    int tid = threadIdx.x;
    int tc = tid & 15, tr = tid >> 4;
#pragma unroll
    for (int rep = 0; rep < 4; rep++) {
        int row = rep * 16 + (tid >> 4);
        int c4 = (tid & 15) * 4;
        float4 va = *(const float4*)(A + ((size_t)bh * Mrows + r0 + row) * DH + c4);
        As[row][c4 + 0] = va.x; As[row][c4 + 1] = va.y; As[row][c4 + 2] = va.z; As[row][c4 + 3] = va.w;
        float4 vb = *(const float4*)(Bm + ((size_t)bh * Ncols + c0 + row) * DH + c4);
        Bs[row][c4 + 0] = vb.x; Bs[row][c4 + 1] = vb.y; Bs[row][c4 + 2] = vb.z; Bs[row][c4 + 3] = vb.w;
    }
    __syncthreads();
    float acc[4][4] = {};
#pragma unroll 8
    for (int kk = 0; kk < DH; kk++) {
        float a_[4], b_[4];
#pragma unroll
        for (int i = 0; i < 4; i++) a_[i] = As[tr * 4 + i][kk];
#pragma unroll
        for (int j = 0; j < 4; j++) b_[j] = Bs[tc * 4 + j][kk];
#pragma unroll
        for (int i = 0; i < 4; i++)
#pragma unroll
            for (int j = 0; j < 4; j++) acc[i][j] += a_[i] * b_[j];
    }
#pragma unroll
    for (int i = 0; i < 4; i++)
#pragma unroll
        for (int j = 0; j < 4; j++)
            C[((size_t)bh * Mrows + r0 + tr * 4 + i) * Ncols + c0 + tc * 4 + j] = acc[i][j];
}

// ---------------- generic row softmax, in place ----------------
__global__ __launch_bounds__(256) void k_softmax(float* __restrict__ S, int len) {
    size_t row = blockIdx.x;
    float* p = S + row * (size_t)len;
    int tid = threadIdx.x;
    __shared__ float red[256];
    float m = -1e30f;
    for (int i = tid; i < len; i += 256) m = fmaxf(m, p[i]);
    red[tid] = m;
    __syncthreads();
    for (int o = 128; o > 0; o >>= 1) { if (tid < o) red[tid] = fmaxf(red[tid], red[tid + o]); __syncthreads(); }
    m = red[0];
    __syncthreads();
    float s = 0.f;
    for (int i = tid; i < len; i += 256) s += __expf(p[i] - m);
    red[tid] = s;
    __syncthreads();
    for (int o = 128; o > 0; o >>= 1) { if (tid < o) red[tid] += red[tid + o]; __syncthreads(); }
    float inv = 1.0f / red[0];
    for (int i = tid; i < len; i += 256) p[i] = __expf(p[i] - m) * inv;
}

// ---------------- pinv scalars: global max row-sum & col-sum of |a2| ----------------
__global__ __launch_bounds__(256) void k_pinv_scal(const float* __restrict__ a2, float* __restrict__ scal) {
    int bh = blockIdx.x, tid = threadIdx.x;
    const float* p = a2 + (size_t)bh * LM * LM;
    float cs = 0.f, rs = 0.f;
    for (int i = 0; i < LM; i++) cs += fabsf(p[(size_t)i * LM + tid]);
    for (int j = 0; j < LM; j++) rs += fabsf(p[(size_t)tid * LM + j]);
    __shared__ float red[256];
    red[tid] = rs;
    __syncthreads();
    for (int o = 128; o > 0; o >>= 1) { if (tid < o) red[tid] = fmaxf(red[tid], red[tid + o]); __syncthreads(); }
    if (tid == 0) atomicMax((int*)&scal[0], __float_as_int(red[0]));
    __syncthreads();
    red[tid] = cs;
    __syncthreads();
    for (int o = 128; o > 0; o >>= 1) { if (tid < o) red[tid] = fmaxf(red[tid], red[tid + o]); __syncthreads(); }
    if (tid == 0) atomicMax((int*)&scal[1], __float_as_int(red[0]));
}

__global__ void k_z0(const float* __restrict__ a2, const float* __restrict__ scal, float* __restrict__ z) {
    int bh = blockIdx.z, i = blockIdx.y, j = threadIdx.x;
    float inv = 1.0f / (scal[0] * scal[1]);
    z[((size_t)bh * LM + i) * LM + j] = a2[((size_t)bh * LM + j) * LM + i] * inv;
}

__global__ void k_diag_sub(const float* __restrict__ in, float* __restrict__ out, float c) {
    size_t idx = (size_t)blockIdx.x * 256 + threadIdx.x;
    int ij = (int)(idx % (LM * LM));
    int i = ij / LM, j = ij % LM;
    out[idx] = ((i == j) ? c : 0.f) - in[idx];
}

// ---------------- batched GEMM (32x32 tile, BK=32): C = alpha*A@B + dval*I ----------------
__global__ __launch_bounds__(256) void k_gemm_b(
        const float* __restrict__ A, const float* __restrict__ Bm, float* __restrict__ C,
        int Mr, int Nc, int Kd, float alpha, float dval) {
    int bh = blockIdx.z;
    int r0 = blockIdx.y * 32, c0 = blockIdx.x * 32;
    const float* Ab = A + (size_t)bh * Mr * Kd;
    const float* Bb = Bm + (size_t)bh * Kd * Nc;
    __shared__ float As[32][33];
    __shared__ float Bs[32][33];
    int tid = threadIdx.x;
    int tr = tid >> 4, tc = tid & 15;
    int lr = tid >> 3, lc = (tid & 7) * 4;
    float acc[2][2] = {};
    for (int k0 = 0; k0 < Kd; k0 += 32) {
        const float* ap = Ab + (size_t)(r0 + lr) * Kd + k0 + lc;
        As[lr][lc + 0] = ap[0]; As[lr][lc + 1] = ap[1]; As[lr][lc + 2] = ap[2]; As[lr][lc + 3] = ap[3];
        const float* bp = Bb + (size_t)(k0 + lr) * Nc + c0 + lc;
        Bs[lr][lc + 0] = bp[0]; Bs[lr][lc + 1] = bp[1]; Bs[lr][lc + 2] = bp[2]; Bs[lr][lc + 3] = bp[3];
        __syncthreads();
#pragma unroll
        for (int kk = 0; kk < 32; kk++) {
            float a0 = As[tr * 2 + 0][kk], a1 = As[tr * 2 + 1][kk];
            float b0 = Bs[kk][tc * 2 + 0], b1 = Bs[kk][tc * 2 + 1];
            acc[0][0] += a0 * b0; acc[0][1] += a0 * b1;
            acc[1][0] += a1 * b0; acc[1][1] += a1 * b1;
        }
        __syncthreads();
    }
#pragma unroll
    for (int i = 0; i < 2; i++)
#pragma unroll
        for (int j = 0; j < 2; j++) {
            int r = r0 + tr * 2 + i, c = c0 + tc * 2 + j;
            float vv = alpha * acc[i][j] + ((r == c) ? dval : 0.f);
            C[(size_t)bh * Mr * Nc + (size_t)r * Nc + c] = vv;
        }
}

// ---------------- P3 @ v, split-K partials ----------------
__global__ __launch_bounds__(256) void k_p3v_partial(
        const float* __restrict__ P3, const float* __restrict__ V, float* __restrict__ part) {
    int bh = blockIdx.z, jt = blockIdx.y, ks = blockIdx.x;
    __shared__ float Ps[64][33];
    __shared__ float Vs[32][DH + 1];
    int tid = threadIdx.x;
    int tr = tid >> 4, tc = tid & 15;
    int j0 = jt * 64;
    float acc[4][4] = {};
    for (int t0 = ks * KCHUNK; t0 < (ks + 1) * KCHUNK; t0 += 32) {
        int lr = tid >> 3, lc = (tid & 7) * 4;
#pragma unroll
        for (int rep = 0; rep < 2; rep++) {
            int rr = lr + rep * 32;
            const float* p = P3 + ((size_t)bh * LM + j0 + rr) * NP + t0 + lc;
            Ps[rr][lc + 0] = p[0]; Ps[rr][lc + 1] = p[1]; Ps[rr][lc + 2] = p[2]; Ps[rr][lc + 3] = p[3];
        }
        int lvr = tid >> 4, lvc = (tid & 15) * 4;
#pragma unroll
        for (int rep = 0; rep < 2; rep++) {
            int rr = lvr + rep * 16;
            const float* p = V + ((size_t)bh * NP + t0 + rr) * DH + lvc;
            Vs[rr][lvc + 0] = p[0]; Vs[rr][lvc + 1] = p[1]; Vs[rr][lvc + 2] = p[2]; Vs[rr][lvc + 3] = p[3];
        }
        __syncthreads();
#pragma unroll
        for (int kk = 0; kk < 32; kk++) {
            float a_[4], b_[4];
#pragma unroll
            for (int i = 0; i < 4; i++) a_[i] = Ps[tr * 4 + i][kk];
#pragma unroll
            for (int j = 0; j < 4; j++) b_[j] = Vs[kk][tc * 4 + j];
#pragma unroll
            for (int i = 0; i < 4; i++)
#pragma unroll
                for (int j = 0; j < 4; j++) acc[i][j] += a_[i] * b_[j];
        }
        __syncthreads();
    }
#pragma unroll
    for (int i = 0; i < 4; i++)
#pragma unroll
        for (int j = 0; j < 4; j++)
            part[(((size_t)bh * KSPLIT + ks) * LM + j0 + tr * 4 + i) * DH + tc * 4 + j] = acc[i][j];
}

__global__ void k_p3v_reduce(const float* __restrict__ part, float* __restrict__ a3v) {
    int idx = blockIdx.x * 256 + threadIdx.x;
    if (idx < BH * LM * DH) {
        int bh = idx / (LM * DH), rest = idx % (LM * DH);
        float s = 0.f;
        for (int ks = 0; ks < KSPLIT; ks++)
            s += part[((size_t)bh * KSPLIT + ks) * LM * DH + rest];
        a3v[idx] = s;
    }
}

// ---------------- out1 = P1 @ M2 -> attn_out (b, tok, h*64+d) ----------------
__global__ __launch_bounds__(256) void k_out1(
        const float* __restrict__ P1, const float* __restrict__ M2, float* __restrict__ attn_out) {
    int bh = blockIdx.z, tt = blockIdx.y;
    int b = bh / NHEADS, hh = bh % NHEADS;
    int tok0 = tt * 64;
    __shared__ float Ps[64][33];
    __shared__ float Ms[32][DH + 1];
    int tid = threadIdx.x;
    int tr = tid >> 4, tc = tid & 15;
    float acc[4][4] = {};
    for (int k0 = 0; k0 < LM; k0 += 32) {
        int lr = tid >> 3, lc = (tid & 7) * 4;
#pragma unroll
        for (int rep = 0; rep < 2; rep++) {
            int rr = lr + rep * 32;
            int tok = tok0 + rr;
            if (tok < NT) {
                const float* p = P1 + ((size_t)bh * NP + tok + PADT) * LM + k0 + lc;
                Ps[rr][lc + 0] = p[0]; Ps[rr][lc + 1] = p[1]; Ps[rr][lc + 2] = p[2]; Ps[rr][lc + 3] = p[3];
            } else {
                Ps[rr][lc + 0] = 0.f; Ps[rr][lc + 1] = 0.f; Ps[rr][lc + 2] = 0.f; Ps[rr][lc + 3] = 0.f;
            }
        }
        int lvr = tid >> 4, lvc = (tid & 15) * 4;
#pragma unroll
        for (int rep = 0; rep < 2; rep++) {
            int rr = lvr + rep * 16;
            const float* p = M2 + ((size_t)bh * LM + k0 + rr) * DH + lvc;
            Ms[rr][lvc + 0] = p[0]; Ms[rr][lvc + 1] = p[1]; Ms[rr][lvc + 2] = p[2]; Ms[rr][lvc + 3] = p[3];
        }
        __syncthreads();
#pragma unroll
        for (int kk = 0; kk < 32; kk++) {
            float a_[4], b_[4];
#pragma unroll
            for (int i = 0; i < 4; i++) a_[i] = Ps[tr * 4 + i][kk];
#pragma unroll
            for (int j = 0; j < 4; j++) b_[j] = Ms[kk][tc * 4 + j];
#pragma unroll
            for (int i = 0; i < 4; i++)
#pragma unroll
                for (int j = 0; j < 4; j++) acc[i][j] += a_[i] * b_[j];
        }
        __syncthreads();
    }
#pragma unroll
    for (int i = 0; i < 4; i++) {
        int tok = tok0 + tr * 4 + i;
        if (tok >= NT) continue;
#pragma unroll
        for (int j = 0; j < 4; j++)
            attn_out[((size_t)b * NT + tok) * DIM + hh * DH + tc * 4 + j] = acc[i][j];
    }
}

// ---------------- residual depthwise conv along tokens (33 taps) ----------------
__global__ __launch_bounds__(256) void k_res_add(
        const float* __restrict__ V, const float* __restrict__ rk, float* __restrict__ attn_out) {
    int bh = blockIdx.y;
    int b = bh / NHEADS, hh = bh % NHEADS;
    int tid = threadIdx.x;
    int tok = blockIdx.x * 4 + (tid >> 6);
    int d = tid & 63;
    __shared__ float k33[33];
    if (tid < 33) k33[tid] = rk[hh * 33 + tid];
    __syncthreads();
    if (tok < NT) {
        int t = tok + PADT;
        float s = 0.f;
#pragma unroll
        for (int u = 0; u < 33; u++) {
            int tp = t - 16 + u;
            if (tp < NP) s += V[((size_t)bh * NP + tp) * DH + d] * k33[u];
        }
        attn_out[((size_t)b * NT + tok) * DIM + hh * DH + d] += s;
    }
}

// ---------------- PPEG ----------------
__global__ void k_combine(const float* __restrict__ k7, const float* __restrict__ b7,
                          const float* __restrict__ k5, const float* __restrict__ b5,
                          const float* __restrict__ k3, const float* __restrict__ b3,
                          float* __restrict__ Kc, float* __restrict__ biasC) {
    int tap = blockIdx.y;
    int c = blockIdx.x * 256 + threadIdx.x;
    if (c >= DIM) return;
    int dy = tap / 7 - 3, dx = tap % 7 - 3;
    int ady = dy < 0 ? -dy : dy, adx = dx < 0 ? -dx : dx;
    float w = k7[(size_t)c * 49 + tap];
    if (ady <= 2 && adx <= 2) w += k5[(size_t)c * 25 + (dy + 2) * 5 + (dx + 2)];
    if (ady <= 1 && adx <= 1) w += k3[(size_t)c * 9 + (dy + 1) * 3 + (dx + 1)];
    if (dy == 0 && dx == 0) w += 1.0f;
    Kc[(size_t)tap * DIM + c] = w;
    if (tap == 0) biasC[c] = b7[c] + b5[c] + b3[c];
}

__global__ __launch_bounds__(256) void k_ppeg(
        const float* __restrict__ h1, const float* __restrict__ Kc,
        const float* __restrict__ biasC, float* __restrict__ h2) {
    int b = blockIdx.z, y = blockIdx.y, x = blockIdx.x;
    int tid = threadIdx.x;
    for (int c = tid; c < DIM; c += 256) {
        float acc = biasC[c];
        for (int dy = -3; dy <= 3; dy++) {
            int iy = y + dy;
            if ((unsigned)iy >= 128u) continue;
            for (int dx = -3; dx <= 3; dx++) {
                int ix = x + dx;
                if ((unsigned)ix >= 128u) continue;
                acc += h1[((size_t)b * NT + 1 + iy * 128 + ix) * DIM + c] *
                       Kc[(size_t)((dy + 3) * 7 + dx + 3) * DIM + c];
            }
        }
        h2[((size_t)b * NT + 1 + y * 128 + x) * DIM + c] = acc;
    }
}

// ---------------- cls-only attention tail (attention #2) ----------------
__global__ __launch_bounds__(256) void k_cls_attn(
        const float* __restrict__ q, const float* __restrict__ kl,
        const float* __restrict__ M2, const float* __restrict__ V,
        const float* __restrict__ rk, float* __restrict__ attn_cls) {
    int bh = blockIdx.x;
    int b = bh / NHEADS, hh = bh % NHEADS;
    int tid = threadIdx.x;
    __shared__ float qr[DH];
    __shared__ float sc[LM];
    __shared__ float red[256];
    if (tid < DH) qr[tid] = q[((size_t)bh * NP + PADT) * DH + tid];
    __syncthreads();
    float s = 0.f;
    const float* kp = kl + ((size_t)bh * LM + tid) * DH;
    for (int d2 = 0; d2 < DH; d2++) s += qr[d2] * kp[d2];
    red[tid] = s;
    __syncthreads();
    for (int o = 128; o > 0; o >>= 1) { if (tid < o) red[tid] = fmaxf(red[tid], red[tid + o]); __syncthreads(); }
    float mx = red[0];
    __syncthreads();
    float e = __expf(s - mx);
    red[tid] = e;
    __syncthreads();
    for (int o = 128; o > 0; o >>= 1) { if (tid < o) red[tid] += red[tid + o]; __syncthreads(); }
    float tot = red[0];
    sc[tid] = e / tot;
    __syncthreads();
    if (tid < DH) {
        int d = tid;
        float o1 = 0.f;
        for (int j = 0; j < LM; j++) o1 += sc[j] * M2[((size_t)bh * LM + j) * DH + d];
        float r2 = 0.f;
        for (int u = 0; u < 33; u++) {
            int tp = PADT - 16 + u;  // 239..271, always in range, pad rows are zero
            r2 += V[((size_t)bh * NP + tp) * DH + d] * rk[hh * 33 + u];
        }
        attn_cls[(size_t)b * DIM + hh * DH + d] = o1 + r2;
    }
}

__global__ __launch_bounds__(256) void k_cls_proj(
        const float* __restrict__ attn_cls, const float* __restrict__ Wout,
        const float* __restrict__ bout, const float* __restrict__ h2, float* __restrict__ h_cls) {
    int b = blockIdx.x, tid = threadIdx.x;
    __shared__ float a[DIM];
    a[tid] = attn_cls[(size_t)b * DIM + tid];
    a[tid + 256] = attn_cls[(size_t)b * DIM + tid + 256];
    __syncthreads();
    for (int c = tid; c < DIM; c += 256) {
        float s = bout[c];
        for (int k2 = 0; k2 < DIM; k2++) s += a[k2] * Wout[(size_t)k2 * DIM + c];
        h_cls[(size_t)b * DIM + c] = h2[(size_t)b * NT * DIM + c] + s;
    }
}

__global__ __launch_bounds__(256) void k_final(
        const float* __restrict__ h_cls, const float* __restrict__ g, const float* __restrict__ bb,
        const float* __restrict__ W2, const float* __restrict__ b2, float* __restrict__ out) {
    int b = blockIdx.x, tid = threadIdx.x;
    const float* x = h_cls + (size_t)b * DIM;
    __shared__ float red[256];
    float v0 = x[tid], v1 = x[tid + 256];
    red[tid] = v0 + v1;
    __syncthreads();
    for (int o = 128; o > 0; o >>= 1) { if (tid < o) red[tid] += red[tid + o]; __syncthreads(); }
    float mu = red[0] * (1.0f / DIM);
    __syncthreads();
    float d0 = v0 - mu, d1 = v1 - mu;
    red[tid] = d0 * d0 + d1 * d1;
    __syncthreads();
    for (int o = 128; o > 0; o >>= 1) { if (tid < o) red[tid] += red[tid + o]; __syncthreads(); }
    float rs = rsqrtf(red[0] * (1.0f / DIM) + LNEPS);
    float y0 = d0 * rs * g[tid] + bb[tid];
    float y1 = d1 * rs * g[tid + 256] + bb[tid + 256];
    red[tid] = y0 * W2[tid] + y1 * W2[tid + 256];
    __syncthreads();
    for (int o = 128; o > 0; o >>= 1) { if (tid < o) red[tid] += red[tid + o]; __syncthreads(); }
    if (tid == 0) out[b] = red[0] + b2[0];
}

// ---------------- host orchestration ----------------
struct AttnBufs {
    float *xln, *q, *k, *v, *ql, *kl;
    float *a2, *za, *zb, *xz, *ta, *tb;
    float *S, *part, *a3v, *M2, *scal;
    float *attn_cls, *h_cls;
};

static void run_attention(hipStream_t stream, const float* hin, float* h_residual,
                          const float* lng, const float* lnb,
                          const float* Wqkv, const float* Wout, const float* bout,
                          const float* resk, bool full, const AttnBufs& B_) {
    // layernorm (pre-pad); padded qkv rows handled via zero-fill
    k_ln<<<dim3(BATCH * NT), 256, 0, stream>>>(hin, lng, lnb, B_.xln);
    k_zero_pads<<<dim3((BH * PADT * DH + 255) / 256), 256, 0, stream>>>(B_.q, B_.k, B_.v);
    k_gemm_qkv<<<dim3(3 * DIM / 64, (BATCH * NT + 63) / 64), 256, 0, stream>>>(B_.xln, Wqkv, B_.q, B_.k, B_.v);
    k_landmark<<<dim3(1, LM, BH), 64, 0, stream>>>(B_.q, B_.ql);
    k_landmark<<<dim3(1, LM, BH), 64, 0, stream>>>(B_.k, B_.kl);
    // attn2 = softmax(q_l k_l^T)
    k_scores<<<dim3(LM / 64, LM / 64, BH), 256, 0, stream>>>(B_.ql, B_.kl, B_.a2, LM, LM);
    k_softmax<<<dim3(BH * LM), 256, 0, stream>>>(B_.a2, LM);
    // Moore-Penrose pinv
    hipMemsetAsync(B_.scal, 0, 2 * sizeof(float), stream);
    k_pinv_scal<<<dim3(BH), 256, 0, stream>>>(B_.a2, B_.scal);
    k_z0<<<dim3(1, LM, BH), 256, 0, stream>>>(B_.a2, B_.scal, B_.za);
    float* zc = B_.za; float* zn = B_.zb;
    for (int it = 0; it < 6; it++) {
        k_gemm_b<<<dim3(8, 8, BH), 256, 0, stream>>>(B_.a2, zc, B_.xz, LM, LM, LM, 1.f, 0.f);
        k_diag_sub<<<dim3(BH * LM * LM / 256), 256, 0, stream>>>(B_.xz, B_.ta, 7.f);
        k_gemm_b<<<dim3(8, 8, BH), 256, 0, stream>>>(B_.xz, B_.ta, B_.tb, LM, LM, LM, -1.f, 15.f);
        k_gemm_b<<<dim3(8, 8, BH), 256, 0, stream>>>(B_.xz, B_.tb, B_.ta, LM, LM, LM, -1.f, 13.f);
        k_gemm_b<<<dim3(8, 8, BH), 256, 0, stream>>>(zc, B_.ta, zn, LM, LM, LM, 0.25f, 0.f);
        std::swap(zc, zn);
    }
    // attn3 path: S3[bh, j, t] = q_l . k ; row softmax over t; then @ v
    k_scores<<<dim3(NP / 64, LM / 64, BH), 256, 0, stream>>>(B_.ql, B_.k, B_.S, LM, NP);
    k_softmax<<<dim3(BH * LM), 256, 0, stream>>>(B_.S, NP);
    k_p3v_partial<<<dim3(KSPLIT, 4, BH), 256, 0, stream>>>(B_.S, B_.v, B_.part);
    k_p3v_reduce<<<dim3(BH * LM * DH / 256), 256, 0, stream>>>(B_.part, B_.a3v);
    // M2 = pinv @ (attn3 @ v)
    k_gemm_b<<<dim3(DH / 32, LM / 32, BH), 256, 0, stream>>>(zc, B_.a3v, B_.M2, LM, DH, LM, 1.f, 0.f);
    if (full) {
        float* attn_out = B_.xln;  // xln dead after qkv; reuse
        k_scores<<<dim3(LM / 64, NP / 64, BH), 256, 0, stream>>>(B_.q, B_.kl, B_.S, NP, LM);
        k_softmax<<<dim3(BH * NP), 256, 0, stream>>>(B_.S, LM);
        k_out1<<<dim3(1, (NT + 63) / 64, BH), 256, 0, stream>>>(B_.S, B_.M2, attn_out);
        k_res_add<<<dim3((NT + 3) / 4, BH), 256, 0, stream>>>(B_.v, resk, attn_out);
        k_gemm_outproj<<<dim3(DIM / 64, (BATCH * NT + 63) / 64), 256, 0, stream>>>(attn_out, Wout, bout, h_residual);
    } else {
        k_cls_attn<<<dim3(BH), 256, 0, stream>>>(B_.q, B_.kl, B_.M2, B_.v, resk, B_.attn_cls);
        k_cls_proj<<<dim3(BATCH), 256, 0, stream>>>(B_.attn_cls, Wout, bout, hin, B_.h_cls);
    }
}

extern "C" void kernel_launch(void* const* d_in, const int* in_sizes, int n_in,
                              void* d_out, int out_size, void* d_ws, size_t ws_size,
                              hipStream_t stream) {
    const float* features = (const float*)d_in[0];
    const float* W1    = (const float*)d_in[1];
    const float* b1    = (const float*)d_in[2];
    const float* cls   = (const float*)d_in[3];
    const float* ln1_g = (const float*)d_in[4];
    const float* ln1_b = (const float*)d_in[5];
    const float* Wqkv1 = (const float*)d_in[6];
    const float* Wout1 = (const float*)d_in[7];
    const float* bout1 = (const float*)d_in[8];
    const float* resk1 = (const float*)d_in[9];
    const float* ln2_g = (const float*)d_in[10];
    const float* ln2_b = (const float*)d_in[11];
    const float* Wqkv2 = (const float*)d_in[12];
    const float* Wout2 = (const float*)d_in[13];
    const float* bout2 = (const float*)d_in[14];
    const float* resk2 = (const float*)d_in[15];
    const float* k7    = (const float*)d_in[16];
    const float* b7c   = (const float*)d_in[17];
    const float* k5    = (const float*)d_in[18];
    const float* b5c   = (const float*)d_in[19];
    const float* k3    = (const float*)d_in[20];
    const float* b3c   = (const float*)d_in[21];
    const float* lnf_g = (const float*)d_in[22];
    const float* lnf_b = (const float*)d_in[23];
    const float* W2    = (const float*)d_in[24];
    const float* b2    = (const float*)d_in[25];
    float* out = (float*)d_out;

    // ---- workspace bump allocator (total ~729 MB fp32) ----
    float* ws = (float*)d_ws;
    size_t off = 0;
    auto alloc = [&](size_t n) { float* p = ws + off; off += (n + 63) & ~(size_t)63; return p; };
    float* h1  = alloc((size_t)BATCH * NT * DIM);
    float* h2  = alloc((size_t)BATCH * NT * DIM);
    AttnBufs Bu;
    Bu.xln  = alloc((size_t)BATCH * NT * DIM);     // also reused as attn_out
    Bu.q    = alloc((size_t)BH * NP * DH);
    Bu.k    = alloc((size_t)BH * NP * DH);
    Bu.v    = alloc((size_t)BH * NP * DH);
    Bu.S    = alloc((size_t)BH * NP * LM);
    Bu.ql   = alloc((size_t)BH * LM * DH);
    Bu.kl   = alloc((size_t)BH * LM * DH);
    Bu.a2   = alloc((size_t)BH * LM * LM);
    Bu.za   = alloc((size_t)BH * LM * LM);
    Bu.zb   = alloc((size_t)BH * LM * LM);
    Bu.xz   = alloc((size_t)BH * LM * LM);
    Bu.ta   = alloc((size_t)BH * LM * LM);
    Bu.tb   = alloc((size_t)BH * LM * LM);
    Bu.part = alloc((size_t)BH * KSPLIT * LM * DH);
    Bu.a3v  = alloc((size_t)BH * LM * DH);
    Bu.M2   = alloc((size_t)BH * LM * DH);
    Bu.scal = alloc(64);
    Bu.attn_cls = alloc(BATCH * DIM);
    Bu.h_cls    = alloc(BATCH * DIM);
    float* Kc    = alloc(49 * DIM);
    float* biasC = alloc(DIM);

    // 1) h = relu(features @ W1 + b1), prepend cls
    k_set_cls<<<dim3(4), 256, 0, stream>>>(cls, h1);
    k_gemm_w1<<<dim3(DIM / 64, BATCH * 16384 / 64), 256, 0, stream>>>(features, W1, b1, h1);
    // 2) h += nystrom_attention(LN(h))  (full)
    run_attention(stream, h1, h1, ln1_g, ln1_b, Wqkv1, Wout1, bout1, resk1, true, Bu);
    // 3) PPEG
    k_combine<<<dim3(2, 49), 256, 0, stream>>>(k7, b7c, k5, b5c, k3, b3c, Kc, biasC);
    k_ppeg<<<dim3(128, 128, BATCH), 256, 0, stream>>>(h1, Kc, biasC, h2);
    k_copy_cls<<<dim3(4), 256, 0, stream>>>(h1, h2);
    // 4) second attention — only cls token output needed downstream
    run_attention(stream, h2, nullptr, ln2_g, ln2_b, Wqkv2, Wout2, bout2, resk2, false, Bu);
    // 5) final LN on cls + linear head
    k_final<<<dim3(BATCH), 256, 0, stream>>>(Bu.h_cls, lnf_g, lnf_b, W2, b2, out);
}

// Round 5
// 4268.161 us; speedup vs baseline: 1.4786x; 1.4786x over previous
//
#include <hip/hip_runtime.h>
#include <utility>

// ---------------- constants ----------------
#define BATCH   2
#define NT      16385          // tokens incl cls
#define NP      16640          // nystrom-padded length (65*256)
#define PADT    255            // front padding
#define LM      256            // landmarks
#define LAVG    65             // tokens averaged per landmark
#define NHEADS  8
#define DH      64
#define DIM     512
#define INDIM   1536
#define BH      (BATCH*NHEADS)
#define LNEPS   1e-5f
#define QSCALE  0.125f
#define KSPLIT  8
#define KCHUNK  2080           // NP / KSPLIT, divisible by 32
#define MROWS   (BATCH*NT)     // 32770
#define MPAD    32896          // 257*128, padded rows for MFMA GEMMs

typedef _Float16 f16x8_t __attribute__((ext_vector_type(8)));
typedef float    f32x4_t __attribute__((ext_vector_type(4)));

// split fp32 -> fp16 hi + fp16 lo (hi+lo carries ~22 mantissa bits)
__device__ __forceinline__ void split2(float f, unsigned short& hi, unsigned short& lo) {
    _Float16 h = (_Float16)f;
    float r = f - (float)h;
    _Float16 l = (_Float16)r;
    hi = __builtin_bit_cast(unsigned short, h);
    lo = __builtin_bit_cast(unsigned short, l);
}

__device__ __forceinline__ void async16(const unsigned short* g, unsigned short* l) {
    __builtin_amdgcn_global_load_lds((const __attribute__((address_space(1))) void*)g,
                                     (__attribute__((address_space(3))) void*)l, 16, 0, 0);
}

// ---------------- tiny kernels ----------------
__global__ void k_set_cls(const float* __restrict__ cls, float* __restrict__ h) {
    int i = blockIdx.x * 256 + threadIdx.x;
    if (i < BATCH * DIM) {
        int b = i / DIM, c = i % DIM;
        h[(size_t)b * NT * DIM + c] = cls[c];
    }
}

__global__ void k_copy_cls(const float* __restrict__ src, float* __restrict__ dst) {
    int i = blockIdx.x * 256 + threadIdx.x;
    if (i < BATCH * DIM) {
        int b = i / DIM, c = i % DIM;
        dst[(size_t)b * NT * DIM + c] = src[(size_t)b * NT * DIM + c];
    }
}

__global__ void k_zero_pads(float* __restrict__ q, float* __restrict__ k, float* __restrict__ v) {
    int idx = blockIdx.x * 256 + threadIdx.x;
    const int per = PADT * DH;
    if (idx < BH * per) {
        int bh = idx / per, rest = idx % per;
        size_t off = (size_t)bh * NP * DH + rest;
        q[off] = 0.f; k[off] = 0.f; v[off] = 0.f;
    }
}

// fp32 -> (hi,lo) fp16 pair, vectorized by 4
__global__ void k_cvt_split(const float* __restrict__ x, unsigned short* __restrict__ yh,
                            unsigned short* __restrict__ yl, int n4) {
    int i = blockIdx.x * 256 + threadIdx.x;
    if (i < n4) {
        float4 v = ((const float4*)x)[i];
        ushort4 oh, ol;
        split2(v.x, oh.x, ol.x); split2(v.y, oh.y, ol.y);
        split2(v.z, oh.z, ol.z); split2(v.w, oh.w, ol.w);
        ((ushort4*)yh)[i] = oh;
        ((ushort4*)yl)[i] = ol;
    }
}

// W [K][N] fp32 -> Wt [N][K] fp16 hi/lo
__global__ void k_wt_split(const float* __restrict__ W, unsigned short* __restrict__ Wth,
                           unsigned short* __restrict__ Wtl, int K, int N) {
    int idx = blockIdx.x * 256 + threadIdx.x;
    if (idx < K * N) {
        int k = idx / N, n = idx % N;
        unsigned short h, l;
        split2(W[idx], h, l);
        Wth[(size_t)n * K + k] = h;
        Wtl[(size_t)n * K + k] = l;
    }
}

// ---------------- split-fp16 MFMA GEMM core: 128x128 tile, BK=32 ----------------
// A = Ah+Al [Mpad][K], Bt = Bh+Bl [N][K]; acc += Ah*Bh + Ah*Bl + Al*Bh (fp32 acc)
__device__ __forceinline__ void mfma_core_s(
        const unsigned short* __restrict__ Ah, const unsigned short* __restrict__ Al,
        const unsigned short* __restrict__ Bh, const unsigned short* __restrict__ Bl,
        int K, int m0, int n0,
        unsigned short* lAh, unsigned short* lAl,
        unsigned short* lBh, unsigned short* lBl, f32x4_t acc[4][4]) {
    const int tid = threadIdx.x;
    const int lane = tid & 63, wave = tid >> 6;
    const int wm = (wave >> 1) * 64, wn = (wave & 1) * 64;
    const int mrow = lane & 15, kg = lane >> 4;
    const int arow = tid >> 2, acol = (tid & 3) * 8;
    for (int k0 = 0; k0 < K; k0 += 32) {
        size_t aoff  = (size_t)(m0 + arow) * K + k0 + acol;
        size_t aoff2 = aoff + (size_t)64 * K;
        size_t boff  = (size_t)(n0 + arow) * K + k0 + acol;
        size_t boff2 = boff + (size_t)64 * K;
        async16(Ah + aoff,  lAh + tid * 8);
        async16(Ah + aoff2, lAh + 2048 + tid * 8);
        async16(Al + aoff,  lAl + tid * 8);
        async16(Al + aoff2, lAl + 2048 + tid * 8);
        async16(Bh + boff,  lBh + tid * 8);
        async16(Bh + boff2, lBh + 2048 + tid * 8);
        async16(Bl + boff,  lBl + tid * 8);
        async16(Bl + boff2, lBl + 2048 + tid * 8);
        __syncthreads();
        f16x8_t ah[4], al[4], bh[4], bl[4];
#pragma unroll
        for (int i = 0; i < 4; i++) {
            int ro = (wm + i * 16 + mrow) * 32 + kg * 8;
            ah[i] = *(const f16x8_t*)(lAh + ro);
            al[i] = *(const f16x8_t*)(lAl + ro);
        }
#pragma unroll
        for (int j = 0; j < 4; j++) {
            int ro = (wn + j * 16 + mrow) * 32 + kg * 8;
            bh[j] = *(const f16x8_t*)(lBh + ro);
            bl[j] = *(const f16x8_t*)(lBl + ro);
        }
#pragma unroll
        for (int i = 0; i < 4; i++)
#pragma unroll
            for (int j = 0; j < 4; j++) {
                acc[i][j] = __builtin_amdgcn_mfma_f32_16x16x32_f16(ah[i], bh[j], acc[i][j], 0, 0, 0);
                acc[i][j] = __builtin_amdgcn_mfma_f32_16x16x32_f16(al[i], bh[j], acc[i][j], 0, 0, 0);
                acc[i][j] = __builtin_amdgcn_mfma_f32_16x16x32_f16(ah[i], bl[j], acc[i][j], 0, 0, 0);
            }
        __syncthreads();
    }
}

#define MFMA_LDS \
    __shared__ __align__(16) unsigned short lAh[4096]; \
    __shared__ __align__(16) unsigned short lAl[4096]; \
    __shared__ __align__(16) unsigned short lBh[4096]; \
    __shared__ __align__(16) unsigned short lBl[4096];

// w1: relu(feat @ W1t + b1) -> h1 (with cls row offset). M=32768, K=1536, N=512
__global__ __launch_bounds__(256) void k_w1_s(
        const unsigned short* __restrict__ Ah, const unsigned short* __restrict__ Al,
        const unsigned short* __restrict__ Bh, const unsigned short* __restrict__ Bl,
        const float* __restrict__ bias, float* __restrict__ hout) {
    MFMA_LDS
    f32x4_t acc[4][4] = {};
    int m0 = blockIdx.y * 128, n0 = blockIdx.x * 128;
    mfma_core_s(Ah, Al, Bh, Bl, INDIM, m0, n0, lAh, lAl, lBh, lBl, acc);
    int lane = threadIdx.x & 63, wave = threadIdx.x >> 6;
    int wm = (wave >> 1) * 64, wn = (wave & 1) * 64;
    int c16 = lane & 15, kg = lane >> 4;
#pragma unroll
    for (int i = 0; i < 4; i++)
#pragma unroll
        for (int r = 0; r < 4; r++) {
            int row = m0 + wm + i * 16 + kg * 4 + r;
            int b = row >> 14;
            size_t orow = (size_t)row + b + 1;
#pragma unroll
            for (int j = 0; j < 4; j++) {
                int col = n0 + wn + j * 16 + c16;
                float v = acc[i][j][r] + bias[col];
                hout[orow * DIM + col] = fmaxf(v, 0.f);
            }
        }
}

// qkv: act @ Wqkvt -> scatter q,k,v. M=32770(pad 32896), K=512, N=1536
__global__ __launch_bounds__(256) void k_qkv_s(
        const unsigned short* __restrict__ Ah, const unsigned short* __restrict__ Al,
        const unsigned short* __restrict__ Bh, const unsigned short* __restrict__ Bl,
        float* __restrict__ q, float* __restrict__ k, float* __restrict__ v) {
    MFMA_LDS
    f32x4_t acc[4][4] = {};
    int m0 = blockIdx.y * 128, n0 = blockIdx.x * 128;
    mfma_core_s(Ah, Al, Bh, Bl, DIM, m0, n0, lAh, lAl, lBh, lBl, acc);
    int lane = threadIdx.x & 63, wave = threadIdx.x >> 6;
    int wm = (wave >> 1) * 64, wn = (wave & 1) * 64;
    int c16 = lane & 15, kg = lane >> 4;
#pragma unroll
    for (int i = 0; i < 4; i++)
#pragma unroll
        for (int r = 0; r < 4; r++) {
            int row = m0 + wm + i * 16 + kg * 4 + r;
            if (row >= MROWS) continue;
            int b = row / NT, tok = row % NT;
            size_t t = (size_t)tok + PADT;
#pragma unroll
            for (int j = 0; j < 4; j++) {
                int col = n0 + wn + j * 16 + c16;
                int sel = col >> 9, hh = (col >> 6) & 7, d = col & 63;
                float vv = acc[i][j][r];
                float* dst = (sel == 0) ? q : (sel == 1) ? k : v;
                if (sel == 0) vv *= QSCALE;
                dst[((size_t)(b * NHEADS + hh) * NP + t) * DH + d] = vv;
            }
        }
}

// outproj: hio += act @ Woutt + bias. M=32770(pad), K=512, N=512
__global__ __launch_bounds__(256) void k_outproj_s(
        const unsigned short* __restrict__ Ah, const unsigned short* __restrict__ Al,
        const unsigned short* __restrict__ Bh, const unsigned short* __restrict__ Bl,
        const float* __restrict__ bias, float* __restrict__ hio) {
    MFMA_LDS
    f32x4_t acc[4][4] = {};
    int m0 = blockIdx.y * 128, n0 = blockIdx.x * 128;
    mfma_core_s(Ah, Al, Bh, Bl, DIM, m0, n0, lAh, lAl, lBh, lBl, acc);
    int lane = threadIdx.x & 63, wave = threadIdx.x >> 6;
    int wm = (wave >> 1) * 64, wn = (wave & 1) * 64;
    int c16 = lane & 15, kg = lane >> 4;
#pragma unroll
    for (int i = 0; i < 4; i++)
#pragma unroll
        for (int r = 0; r < 4; r++) {
            int row = m0 + wm + i * 16 + kg * 4 + r;
            if (row >= MROWS) continue;
#pragma unroll
            for (int j = 0; j < 4; j++) {
                int col = n0 + wn + j * 16 + c16;
                hio[(size_t)row * DIM + col] += acc[i][j][r] + bias[col];
            }
        }
}

// ---------------- layernorm -> split fp16 ----------------
__global__ __launch_bounds__(256) void k_ln_split(
        const float* __restrict__ x, const float* __restrict__ g,
        const float* __restrict__ bb, unsigned short* __restrict__ yh,
        unsigned short* __restrict__ yl) {
    size_t row = blockIdx.x;
    const float* xr = x + row * DIM;
    int tid = threadIdx.x;
    __shared__ float red[256];
    float v0 = xr[tid], v1 = xr[tid + 256];
    red[tid] = v0 + v1;
    __syncthreads();
    for (int o = 128; o > 0; o >>= 1) { if (tid < o) red[tid] += red[tid + o]; __syncthreads(); }
    float mu = red[0] * (1.0f / DIM);
    __syncthreads();
    float d0 = v0 - mu, d1 = v1 - mu;
    red[tid] = d0 * d0 + d1 * d1;
    __syncthreads();
    for (int o = 128; o > 0; o >>= 1) { if (tid < o) red[tid] += red[tid + o]; __syncthreads(); }
    float rs = rsqrtf(red[0] * (1.0f / DIM) + LNEPS);
    float y0 = d0 * rs * g[tid] + bb[tid];
    float y1 = d1 * rs * g[tid + 256] + bb[tid + 256];
    unsigned short h, l;
    split2(y0, h, l);
    yh[row * DIM + tid] = h; yl[row * DIM + tid] = l;
    split2(y1, h, l);
    yh[row * DIM + tid + 256] = h; yl[row * DIM + tid + 256] = l;
}

// ---------------- landmarks ----------------
__global__ void k_landmark(const float* __restrict__ x, float* __restrict__ xl) {
    int bh = blockIdx.z, i = blockIdx.y, d = threadIdx.x;
    const float* p = x + ((size_t)bh * NP + (size_t)i * LAVG) * DH + d;
    float s = 0.f;
    for (int j = 0; j < LAVG; j++) s += p[(size_t)j * DH];
    xl[((size_t)bh * LM + i) * DH + d] = s * (1.0f / LAVG);
}

// ---------------- scores: C[bh,r,c] = A[bh,r,:]·B[bh,c,:]  (K=64) ----------------
__global__ __launch_bounds__(256) void k_scores(
        const float* __restrict__ A, const float* __restrict__ Bm,
        float* __restrict__ C, int Mrows, int Ncols) {
    int bh = blockIdx.z;
    int c0 = blockIdx.x * 64, r0 = blockIdx.y * 64;
    __shared__ float As[64][DH + 1];
    __shared__ float Bs[64][DH + 1];
    int tid = threadIdx.x;
    int tc = tid & 15, tr = tid >> 4;
#pragma unroll
    for (int rep = 0; rep < 4; rep++) {
        int row = rep * 16 + (tid >> 4);
        int c4 = (tid & 15) * 4;
        float4 va = *(const float4*)(A + ((size_t)bh * Mrows + r0 + row) * DH + c4);
        As[row][c4 + 0] = va.x; As[row][c4 + 1] = va.y; As[row][c4 + 2] = va.z; As[row][c4 + 3] = va.w;
        float4 vb = *(const float4*)(Bm + ((size_t)bh * Ncols + c0 + row) * DH + c4);
        Bs[row][c4 + 0] = vb.x; Bs[row][c4 + 1] = vb.y; Bs[row][c4 + 2] = vb.z; Bs[row][c4 + 3] = vb.w;
    }
    __syncthreads();
    float acc[4][4] = {};
#pragma unroll 8
    for (int kk = 0; kk < DH; kk++) {
        float a_[4], b_[4];
#pragma unroll
        for (int i = 0; i < 4; i++) a_[i] = As[tr * 4 + i][kk];
#pragma unroll
        for (int j = 0; j < 4; j++) b_[j] = Bs[tc * 4 + j][kk];
#pragma unroll
        for (int i = 0; i < 4; i++)
#pragma unroll
            for (int j = 0; j < 4; j++) acc[i][j] += a_[i] * b_[j];
    }
#pragma unroll
    for (int i = 0; i < 4; i++)
#pragma unroll
        for (int j = 0; j < 4; j++)
            C[((size_t)bh * Mrows + r0 + tr * 4 + i) * Ncols + c0 + tc * 4 + j] = acc[i][j];
}

// ---------------- row softmax, in place ----------------
__global__ __launch_bounds__(256) void k_softmax(float* __restrict__ S, int len) {
    size_t row = blockIdx.x;
    float* p = S + row * (size_t)len;
    int tid = threadIdx.x;
    __shared__ float red[256];
    float m = -1e30f;
    for (int i = tid; i < len; i += 256) m = fmaxf(m, p[i]);
    red[tid] = m;
    __syncthreads();
    for (int o = 128; o > 0; o >>= 1) { if (tid < o) red[tid] = fmaxf(red[tid], red[tid + o]); __syncthreads(); }
    m = red[0];
    __syncthreads();
    float s = 0.f;
    for (int i = tid; i < len; i += 256) s += __expf(p[i] - m);
    red[tid] = s;
    __syncthreads();
    for (int o = 128; o > 0; o >>= 1) { if (tid < o) red[tid] += red[tid + o]; __syncthreads(); }
    float inv = 1.0f / red[0];
    for (int i = tid; i < len; i += 256) p[i] = __expf(p[i] - m) * inv;
}

// ---------------- pinv scalars ----------------
__global__ __launch_bounds__(256) void k_pinv_scal(const float* __restrict__ a2, float* __restrict__ scal) {
    int bh = blockIdx.x, tid = threadIdx.x;
    const float* p = a2 + (size_t)bh * LM * LM;
    float cs = 0.f, rs = 0.f;
    for (int i = 0; i < LM; i++) cs += fabsf(p[(size_t)i * LM + tid]);
    for (int j = 0; j < LM; j++) rs += fabsf(p[(size_t)tid * LM + j]);
    __shared__ float red[256];
    red[tid] = rs;
    __syncthreads();
    for (int o = 128; o > 0; o >>= 1) { if (tid < o) red[tid] = fmaxf(red[tid], red[tid + o]); __syncthreads(); }
    if (tid == 0) atomicMax((int*)&scal[0], __float_as_int(red[0]));
    __syncthreads();
    red[tid] = cs;
    __syncthreads();
    for (int o = 128; o > 0; o >>= 1) { if (tid < o) red[tid] = fmaxf(red[tid], red[tid + o]); __syncthreads(); }
    if (tid == 0) atomicMax((int*)&scal[1], __float_as_int(red[0]));
}

__global__ void k_z0(const float* __restrict__ a2, const float* __restrict__ scal, float* __restrict__ z) {
    int bh = blockIdx.z, i = blockIdx.y, j = threadIdx.x;
    float inv = 1.0f / (scal[0] * scal[1]);
    z[((size_t)bh * LM + i) * LM + j] = a2[((size_t)bh * LM + j) * LM + i] * inv;
}

__global__ void k_diag_sub(const float* __restrict__ in, float* __restrict__ out, float c) {
    size_t idx = (size_t)blockIdx.x * 256 + threadIdx.x;
    int ij = (int)(idx % (LM * LM));
    int i = ij / LM, j = ij % LM;
    out[idx] = ((i == j) ? c : 0.f) - in[idx];
}

// ---------------- batched fp32 GEMM, 64x64 tile, BK=32, 4x4/thread ----------------
__global__ __launch_bounds__(256) void k_gemm_b64(
        const float* __restrict__ A, const float* __restrict__ Bm, float* __restrict__ C,
        int Mr, int Nc, int Kd, float alpha, float dval) {
    int bh = blockIdx.z;
    int r0 = blockIdx.y * 64, c0 = blockIdx.x * 64;
    const float* Ab = A + (size_t)bh * Mr * Kd;
    const float* Bb = Bm + (size_t)bh * Kd * Nc;
    __shared__ float As[64][36];
    __shared__ float Bs[32][68];
    int tid = threadIdx.x;
    int tr = tid >> 4, tc = tid & 15;
    int arw = tid >> 2, ac8 = (tid & 3) * 8;
    int brw = tid >> 3, bc8 = (tid & 7) * 8;
    float acc[4][4] = {};
    for (int k0 = 0; k0 < Kd; k0 += 32) {
        float4 a0 = *(const float4*)(Ab + (size_t)(r0 + arw) * Kd + k0 + ac8);
        float4 a1 = *(const float4*)(Ab + (size_t)(r0 + arw) * Kd + k0 + ac8 + 4);
        *(float4*)&As[arw][ac8] = a0;
        *(float4*)&As[arw][ac8 + 4] = a1;
        float4 b0 = *(const float4*)(Bb + (size_t)(k0 + brw) * Nc + c0 + bc8);
        float4 b1 = *(const float4*)(Bb + (size_t)(k0 + brw) * Nc + c0 + bc8 + 4);
        *(float4*)&Bs[brw][bc8] = b0;
        *(float4*)&Bs[brw][bc8 + 4] = b1;
        __syncthreads();
#pragma unroll
        for (int kk = 0; kk < 32; kk++) {
            float a_[4], b_[4];
#pragma unroll
            for (int i = 0; i < 4; i++) a_[i] = As[tr * 4 + i][kk];
#pragma unroll
            for (int j = 0; j < 4; j++) b_[j] = Bs[kk][tc * 4 + j];
#pragma unroll
            for (int i = 0; i < 4; i++)
#pragma unroll
                for (int j = 0; j < 4; j++) acc[i][j] += a_[i] * b_[j];
        }
        __syncthreads();
    }
#pragma unroll
    for (int i = 0; i < 4; i++)
#pragma unroll
        for (int j = 0; j < 4; j++) {
            int r = r0 + tr * 4 + i, c = c0 + tc * 4 + j;
            float vv = alpha * acc[i][j] + ((r == c) ? dval : 0.f);
            C[(size_t)bh * Mr * Nc + (size_t)r * Nc + c] = vv;
        }
}

// ---------------- P3 @ v, split-K partials ----------------
__global__ __launch_bounds__(256) void k_p3v_partial(
        const float* __restrict__ P3, const float* __restrict__ V, float* __restrict__ part) {
    int bh = blockIdx.z, jt = blockIdx.y, ks = blockIdx.x;
    __shared__ float Ps[64][33];
    __shared__ float Vs[32][DH + 1];
    int tid = threadIdx.x;
    int tr = tid >> 4, tc = tid & 15;
    int j0 = jt * 64;
    float acc[4][4] = {};
    for (int t0 = ks * KCHUNK; t0 < (ks + 1) * KCHUNK; t0 += 32) {
        int lr = tid >> 3, lc = (tid & 7) * 4;
#pragma unroll
        for (int rep = 0; rep < 2; rep++) {
            int rr = lr + rep * 32;
            const float* p = P3 + ((size_t)bh * LM + j0 + rr) * NP + t0 + lc;
            Ps[rr][lc + 0] = p[0]; Ps[rr][lc + 1] = p[1]; Ps[rr][lc + 2] = p[2]; Ps[rr][lc + 3] = p[3];
        }
        int lvr = tid >> 4, lvc = (tid & 15) * 4;
#pragma unroll
        for (int rep = 0; rep < 2; rep++) {
            int rr = lvr + rep * 16;
            const float* p = V + ((size_t)bh * NP + t0 + rr) * DH + lvc;
            Vs[rr][lvc + 0] = p[0]; Vs[rr][lvc + 1] = p[1]; Vs[rr][lvc + 2] = p[2]; Vs[rr][lvc + 3] = p[3];
        }
        __syncthreads();
#pragma unroll
        for (int kk = 0; kk < 32; kk++) {
            float a_[4], b_[4];
#pragma unroll
            for (int i = 0; i < 4; i++) a_[i] = Ps[tr * 4 + i][kk];
#pragma unroll
            for (int j = 0; j < 4; j++) b_[j] = Vs[kk][tc * 4 + j];
#pragma unroll
            for (int i = 0; i < 4; i++)
#pragma unroll
                for (int j = 0; j < 4; j++) acc[i][j] += a_[i] * b_[j];
        }
        __syncthreads();
    }
#pragma unroll
    for (int i = 0; i < 4; i++)
#pragma unroll
        for (int j = 0; j < 4; j++)
            part[(((size_t)bh * KSPLIT + ks) * LM + j0 + tr * 4 + i) * DH + tc * 4 + j] = acc[i][j];
}

__global__ void k_p3v_reduce(const float* __restrict__ part, float* __restrict__ a3v) {
    int idx = blockIdx.x * 256 + threadIdx.x;
    if (idx < BH * LM * DH) {
        int bh = idx / (LM * DH), rest = idx % (LM * DH);
        float s = 0.f;
        for (int ks = 0; ks < KSPLIT; ks++)
            s += part[((size_t)bh * KSPLIT + ks) * LM * DH + rest];
        a3v[idx] = s;
    }
}

// ---------------- out1 = P1 @ M2 ----------------
__global__ __launch_bounds__(256) void k_out1(
        const float* __restrict__ P1, const float* __restrict__ M2, float* __restrict__ attn_out) {
    int bh = blockIdx.z, tt = blockIdx.y;
    int b = bh / NHEADS, hh = bh % NHEADS;
    int tok0 = tt * 64;
    __shared__ float Ps[64][33];
    __shared__ float Ms[32][DH + 1];
    int tid = threadIdx.x;
    int tr = tid >> 4, tc = tid & 15;
    float acc[4][4] = {};
    for (int k0 = 0; k0 < LM; k0 += 32) {
        int lr = tid >> 3, lc = (tid & 7) * 4;
#pragma unroll
        for (int rep = 0; rep < 2; rep++) {
            int rr = lr + rep * 32;
            int tok = tok0 + rr;
            if (tok < NT) {
                const float* p = P1 + ((size_t)bh * NP + tok + PADT) * LM + k0 + lc;
                Ps[rr][lc + 0] = p[0]; Ps[rr][lc + 1] = p[1]; Ps[rr][lc + 2] = p[2]; Ps[rr][lc + 3] = p[3];
            } else {
                Ps[rr][lc + 0] = 0.f; Ps[rr][lc + 1] = 0.f; Ps[rr][lc + 2] = 0.f; Ps[rr][lc + 3] = 0.f;
            }
        }
        int lvr = tid >> 4, lvc = (tid & 15) * 4;
#pragma unroll
        for (int rep = 0; rep < 2; rep++) {
            int rr = lvr + rep * 16;
            const float* p = M2 + ((size_t)bh * LM + k0 + rr) * DH + lvc;
            Ms[rr][lvc + 0] = p[0]; Ms[rr][lvc + 1] = p[1]; Ms[rr][lvc + 2] = p[2]; Ms[rr][lvc + 3] = p[3];
        }
        __syncthreads();
#pragma unroll
        for (int kk = 0; kk < 32; kk++) {
            float a_[4], b_[4];
#pragma unroll
            for (int i = 0; i < 4; i++) a_[i] = Ps[tr * 4 + i][kk];
#pragma unroll
            for (int j = 0; j < 4; j++) b_[j] = Ms[kk][tc * 4 + j];
#pragma unroll
            for (int i = 0; i < 4; i++)
#pragma unroll
                for (int j = 0; j < 4; j++) acc[i][j] += a_[i] * b_[j];
        }
        __syncthreads();
    }
#pragma unroll
    for (int i = 0; i < 4; i++) {
        int tok = tok0 + tr * 4 + i;
        if (tok >= NT) continue;
#pragma unroll
        for (int j = 0; j < 4; j++)
            attn_out[((size_t)b * NT + tok) * DIM + hh * DH + tc * 4 + j] = acc[i][j];
    }
}

// ---------------- residual depthwise conv along tokens ----------------
__global__ __launch_bounds__(256) void k_res_add(
        const float* __restrict__ V, const float* __restrict__ rk, float* __restrict__ attn_out) {
    int bh = blockIdx.y;
    int b = bh / NHEADS, hh = bh % NHEADS;
    int tid = threadIdx.x;
    int tok = blockIdx.x * 4 + (tid >> 6);
    int d = tid & 63;
    __shared__ float k33[33];
    if (tid < 33) k33[tid] = rk[hh * 33 + tid];
    __syncthreads();
    if (tok < NT) {
        int t = tok + PADT;
        float s = 0.f;
#pragma unroll
        for (int u = 0; u < 33; u++) {
            int tp = t - 16 + u;
            if (tp < NP) s += V[((size_t)bh * NP + tp) * DH + d] * k33[u];
        }
        attn_out[((size_t)b * NT + tok) * DIM + hh * DH + d] += s;
    }
}

// ---------------- PPEG ----------------
__global__ void k_combine(const float* __restrict__ k7, const float* __restrict__ b7,
                          const float* __restrict__ k5, const float* __restrict__ b5,
                          const float* __restrict__ k3, const float* __restrict__ b3,
                          float* __restrict__ Kc, float* __restrict__ biasC) {
    int tap = blockIdx.y;
    int c = blockIdx.x * 256 + threadIdx.x;
    if (c >= DIM) return;
    int dy = tap / 7 - 3, dx = tap % 7 - 3;
    int ady = dy < 0 ? -dy : dy, adx = dx < 0 ? -dx : dx;
    float w = k7[(size_t)c * 49 + tap];
    if (ady <= 2 && adx <= 2) w += k5[(size_t)c * 25 + (dy + 2) * 5 + (dx + 2)];
    if (ady <= 1 && adx <= 1) w += k3[(size_t)c * 9 + (dy + 1) * 3 + (dx + 1)];
    if (dy == 0 && dx == 0) w += 1.0f;
    Kc[(size_t)tap * DIM + c] = w;
    if (tap == 0) biasC[c] = b7[c] + b5[c] + b3[c];
}

// LDS-tiled PPEG: 32x32 pixel tile, 8-channel group, halo 3
#define PT 32
#define PH 38
__global__ __launch_bounds__(256) void k_ppeg2(
        const float* __restrict__ h1, const float* __restrict__ Kc,
        const float* __restrict__ biasC, float* __restrict__ h2) {
    int xt = blockIdx.x, yt = blockIdx.y;
    int bz = blockIdx.z;
    int b = bz >> 6, cg = bz & 63, c0 = cg * 8;
    __shared__ __align__(16) float sin2[PH * PH * 8];
    __shared__ __align__(16) float wk2[49 * 8];
    __shared__ float sb[8];
    int tid = threadIdx.x;
    // FIX (round 4): 392 entries > 256 threads — must stride, taps 32..48 were garbage
    for (int i2 = tid; i2 < 392; i2 += 256) {
        int tap = i2 >> 3, ch = i2 & 7;
        wk2[tap * 8 + ch] = Kc[(size_t)tap * DIM + c0 + ch];
    }
    if (tid < 8) sb[tid] = biasC[c0 + tid];
    for (int p = tid; p < PH * PH; p += 256) {
        int ly = p / PH, lx = p % PH;
        int gy = yt * PT + ly - 3, gx = xt * PT + lx - 3;
        float4 v0 = make_float4(0.f, 0.f, 0.f, 0.f), v1 = v0;
        if ((unsigned)gy < 128u && (unsigned)gx < 128u) {
            const float* src = h1 + ((size_t)b * NT + 1 + (size_t)gy * 128 + gx) * DIM + c0;
            v0 = *(const float4*)src;
            v1 = *(const float4*)(src + 4);
        }
        *(float4*)&sin2[p * 8] = v0;
        *(float4*)&sin2[p * 8 + 4] = v1;
    }
    __syncthreads();
    int px = tid & 31, py0 = tid >> 5;
    for (int ry = 0; ry < 4; ry++) {
        int py = py0 + ry * 8;
        float accv[8];
#pragma unroll
        for (int ch = 0; ch < 8; ch++) accv[ch] = sb[ch];
        for (int dy = 0; dy < 7; dy++)
#pragma unroll
            for (int dx = 0; dx < 7; dx++) {
                int pi = (py + dy) * PH + px + dx;
                float4 s0 = *(const float4*)&sin2[pi * 8];
                float4 s1 = *(const float4*)&sin2[pi * 8 + 4];
                int tp = dy * 7 + dx;
                float4 w0 = *(const float4*)&wk2[tp * 8];
                float4 w1 = *(const float4*)&wk2[tp * 8 + 4];
                accv[0] += s0.x * w0.x; accv[1] += s0.y * w0.y;
                accv[2] += s0.z * w0.z; accv[3] += s0.w * w0.w;
                accv[4] += s1.x * w1.x; accv[5] += s1.y * w1.y;
                accv[6] += s1.z * w1.z; accv[7] += s1.w * w1.w;
            }
        float* dst = h2 + ((size_t)b * NT + 1 + (size_t)(yt * PT + py) * 128 + xt * PT + px) * DIM + c0;
        *(float4*)dst = make_float4(accv[0], accv[1], accv[2], accv[3]);
        *(float4*)(dst + 4) = make_float4(accv[4], accv[5], accv[6], accv[7]);
    }
}

// ---------------- cls-only attention tail (attention #2) ----------------
__global__ __launch_bounds__(256) void k_cls_attn(
        const float* __restrict__ q, const float* __restrict__ kl,
        const float* __restrict__ M2, const float* __restrict__ V,
        const float* __restrict__ rk, float* __restrict__ attn_cls) {
    int bh = blockIdx.x;
    int b = bh / NHEADS, hh = bh % NHEADS;
    int tid = threadIdx.x;
    __shared__ float qr[DH];
    __shared__ float sc[LM];
    __shared__ float red[256];
    if (tid < DH) qr[tid] = q[((size_t)bh * NP + PADT) * DH + tid];
    __syncthreads();
    float s = 0.f;
    const float* kp = kl + ((size_t)bh * LM + tid) * DH;
    for (int d2 = 0; d2 < DH; d2++) s += qr[d2] * kp[d2];
    red[tid] = s;
    __syncthreads();
    for (int o = 128; o > 0; o >>= 1) { if (tid < o) red[tid] = fmaxf(red[tid], red[tid + o]); __syncthreads(); }
    float mx = red[0];
    __syncthreads();
    float e = __expf(s - mx);
    red[tid] = e;
    __syncthreads();
    for (int o = 128; o > 0; o >>= 1) { if (tid < o) red[tid] += red[tid + o]; __syncthreads(); }
    float tot = red[0];
    sc[tid] = e / tot;
    __syncthreads();
    if (tid < DH) {
        int d = tid;
        float o1 = 0.f;
        for (int j = 0; j < LM; j++) o1 += sc[j] * M2[((size_t)bh * LM + j) * DH + d];
        float r2 = 0.f;
        for (int u = 0; u < 33; u++) {
            int tp = PADT - 16 + u;
            r2 += V[((size_t)bh * NP + tp) * DH + d] * rk[hh * 33 + u];
        }
        attn_cls[(size_t)b * DIM + hh * DH + d] = o1 + r2;
    }
}

__global__ __launch_bounds__(256) void k_cls_proj(
        const float* __restrict__ attn_cls, const float* __restrict__ Wout,
        const float* __restrict__ bout, const float* __restrict__ h2, float* __restrict__ h_cls) {
    int b = blockIdx.x, tid = threadIdx.x;
    __shared__ float a[DIM];
    a[tid] = attn_cls[(size_t)b * DIM + tid];
    a[tid + 256] = attn_cls[(size_t)b * DIM + tid + 256];
    __syncthreads();
    for (int c = tid; c < DIM; c += 256) {
        float s = bout[c];
        for (int k2 = 0; k2 < DIM; k2++) s += a[k2] * Wout[(size_t)k2 * DIM + c];
        h_cls[(size_t)b * DIM + c] = h2[(size_t)b * NT * DIM + c] + s;
    }
}

__global__ __launch_bounds__(256) void k_final(
        const float* __restrict__ h_cls, const float* __restrict__ g, const float* __restrict__ bb,
        const float* __restrict__ W2, const float* __restrict__ b2, float* __restrict__ out) {
    int b = blockIdx.x, tid = threadIdx.x;
    const float* x = h_cls + (size_t)b * DIM;
    __shared__ float red[256];
    float v0 = x[tid], v1 = x[tid + 256];
    red[tid] = v0 + v1;
    __syncthreads();
    for (int o = 128; o > 0; o >>= 1) { if (tid < o) red[tid] += red[tid + o]; __syncthreads(); }
    float mu = red[0] * (1.0f / DIM);
    __syncthreads();
    float d0 = v0 - mu, d1 = v1 - mu;
    red[tid] = d0 * d0 + d1 * d1;
    __syncthreads();
    for (int o = 128; o > 0; o >>= 1) { if (tid < o) red[tid] += red[tid + o]; __syncthreads(); }
    float rs = rsqrtf(red[0] * (1.0f / DIM) + LNEPS);
    float y0 = d0 * rs * g[tid] + bb[tid];
    float y1 = d1 * rs * g[tid + 256] + bb[tid + 256];
    red[tid] = y0 * W2[tid] + y1 * W2[tid + 256];
    __syncthreads();
    for (int o = 128; o > 0; o >>= 1) { if (tid < o) red[tid] += red[tid + o]; __syncthreads(); }
    if (tid == 0) out[b] = red[0] + b2[0];
}

// ---------------- host orchestration ----------------
struct AttnBufs {
    float *q, *k, *v, *ql, *kl;
    float *a2, *za, *zb, *xz, *ta, *tb;
    float *S, *part, *a3v, *M2, *scal;
    float *attn_cls, *h_cls;
    unsigned short *actb_h, *actb_l;
};

static void run_attention(hipStream_t stream, const float* hin, float* h_residual,
                          float* attn_out,
                          const float* lng, const float* lnb,
                          const unsigned short* Wqkvt_h, const unsigned short* Wqkvt_l,
                          const unsigned short* Woutt_h, const unsigned short* Woutt_l,
                          const float* Wout_f32, const float* bout,
                          const float* resk, bool full, const AttnBufs& B_) {
    k_ln_split<<<dim3(BATCH * NT), 256, 0, stream>>>(hin, lng, lnb, B_.actb_h, B_.actb_l);
    k_zero_pads<<<dim3((BH * PADT * DH + 255) / 256), 256, 0, stream>>>(B_.q, B_.k, B_.v);
    k_qkv_s<<<dim3(12, MPAD / 128), 256, 0, stream>>>(B_.actb_h, B_.actb_l, Wqkvt_h, Wqkvt_l, B_.q, B_.k, B_.v);
    k_landmark<<<dim3(1, LM, BH), 64, 0, stream>>>(B_.q, B_.ql);
    k_landmark<<<dim3(1, LM, BH), 64, 0, stream>>>(B_.k, B_.kl);
    k_scores<<<dim3(LM / 64, LM / 64, BH), 256, 0, stream>>>(B_.ql, B_.kl, B_.a2, LM, LM);
    k_softmax<<<dim3(BH * LM), 256, 0, stream>>>(B_.a2, LM);
    hipMemsetAsync(B_.scal, 0, 2 * sizeof(float), stream);
    k_pinv_scal<<<dim3(BH), 256, 0, stream>>>(B_.a2, B_.scal);
    k_z0<<<dim3(1, LM, BH), 256, 0, stream>>>(B_.a2, B_.scal, B_.za);
    float* zc = B_.za; float* zn = B_.zb;
    for (int it = 0; it < 6; it++) {
        k_gemm_b64<<<dim3(4, 4, BH), 256, 0, stream>>>(B_.a2, zc, B_.xz, LM, LM, LM, 1.f, 0.f);
        k_diag_sub<<<dim3(BH * LM * LM / 256), 256, 0, stream>>>(B_.xz, B_.ta, 7.f);
        k_gemm_b64<<<dim3(4, 4, BH), 256, 0, stream>>>(B_.xz, B_.ta, B_.tb, LM, LM, LM, -1.f, 15.f);
        k_gemm_b64<<<dim3(4, 4, BH), 256, 0, stream>>>(B_.xz, B_.tb, B_.ta, LM, LM, LM, -1.f, 13.f);
        k_gemm_b64<<<dim3(4, 4, BH), 256, 0, stream>>>(zc, B_.ta, zn, LM, LM, LM, 0.25f, 0.f);
        std::swap(zc, zn);
    }
    k_scores<<<dim3(NP / 64, LM / 64, BH), 256, 0, stream>>>(B_.ql, B_.k, B_.S, LM, NP);
    k_softmax<<<dim3(BH * LM), 256, 0, stream>>>(B_.S, NP);
    k_p3v_partial<<<dim3(KSPLIT, 4, BH), 256, 0, stream>>>(B_.S, B_.v, B_.part);
    k_p3v_reduce<<<dim3(BH * LM * DH / 256), 256, 0, stream>>>(B_.part, B_.a3v);
    k_gemm_b64<<<dim3(1, 4, BH), 256, 0, stream>>>(zc, B_.a3v, B_.M2, LM, DH, LM, 1.f, 0.f);
    if (full) {
        k_scores<<<dim3(LM / 64, NP / 64, BH), 256, 0, stream>>>(B_.q, B_.kl, B_.S, NP, LM);
        k_softmax<<<dim3(BH * NP), 256, 0, stream>>>(B_.S, LM);
        k_out1<<<dim3(1, (NT + 63) / 64, BH), 256, 0, stream>>>(B_.S, B_.M2, attn_out);
        k_res_add<<<dim3((NT + 3) / 4, BH), 256, 0, stream>>>(B_.v, resk, attn_out);
        k_cvt_split<<<dim3((MROWS * DIM / 4 + 255) / 256), 256, 0, stream>>>(attn_out, B_.actb_h, B_.actb_l, MROWS * DIM / 4);
        k_outproj_s<<<dim3(4, MPAD / 128), 256, 0, stream>>>(B_.actb_h, B_.actb_l, Woutt_h, Woutt_l, bout, h_residual);
    } else {
        k_cls_attn<<<dim3(BH), 256, 0, stream>>>(B_.q, B_.kl, B_.M2, B_.v, resk, B_.attn_cls);
        k_cls_proj<<<dim3(BATCH), 256, 0, stream>>>(B_.attn_cls, Wout_f32, bout, hin, B_.h_cls);
    }
}

extern "C" void kernel_launch(void* const* d_in, const int* in_sizes, int n_in,
                              void* d_out, int out_size, void* d_ws, size_t ws_size,
                              hipStream_t stream) {
    const float* features = (const float*)d_in[0];
    const float* W1    = (const float*)d_in[1];
    const float* b1    = (const float*)d_in[2];
    const float* cls   = (const float*)d_in[3];
    const float* ln1_g = (const float*)d_in[4];
    const float* ln1_b = (const float*)d_in[5];
    const float* Wqkv1 = (const float*)d_in[6];
    const float* Wout1 = (const float*)d_in[7];
    const float* bout1 = (const float*)d_in[8];
    const float* resk1 = (const float*)d_in[9];
    const float* ln2_g = (const float*)d_in[10];
    const float* ln2_b = (const float*)d_in[11];
    const float* Wqkv2 = (const float*)d_in[12];
    const float* Wout2 = (const float*)d_in[13];
    const float* bout2 = (const float*)d_in[14];
    const float* resk2 = (const float*)d_in[15];
    const float* k7    = (const float*)d_in[16];
    const float* b7c   = (const float*)d_in[17];
    const float* k5    = (const float*)d_in[18];
    const float* b5c   = (const float*)d_in[19];
    const float* k3    = (const float*)d_in[20];
    const float* b3c   = (const float*)d_in[21];
    const float* lnf_g = (const float*)d_in[22];
    const float* lnf_b = (const float*)d_in[23];
    const float* W2    = (const float*)d_in[24];
    const float* b2    = (const float*)d_in[25];
    float* out = (float*)d_out;

    float* ws = (float*)d_ws;
    size_t off = 0;
    auto alloc = [&](size_t n) { float* p = ws + off; off += (n + 63) & ~(size_t)63; return p; };
    float* h1  = alloc((size_t)BATCH * NT * DIM);
    float* h2  = alloc((size_t)BATCH * NT * DIM);   // also attn_out of layer 1
    AttnBufs Bu;
    Bu.q    = alloc((size_t)BH * NP * DH);
    Bu.k    = alloc((size_t)BH * NP * DH);
    Bu.v    = alloc((size_t)BH * NP * DH);
    Bu.S    = alloc((size_t)BH * NP * LM);          // also aliased as feat hi/lo (f16)
    Bu.ql   = alloc((size_t)BH * LM * DH);
    Bu.kl   = alloc((size_t)BH * LM * DH);
    Bu.a2   = alloc((size_t)BH * LM * LM);
    Bu.za   = alloc((size_t)BH * LM * LM);
    Bu.zb   = alloc((size_t)BH * LM * LM);
    Bu.xz   = alloc((size_t)BH * LM * LM);
    Bu.ta   = alloc((size_t)BH * LM * LM);
    Bu.tb   = alloc((size_t)BH * LM * LM);
    Bu.part = alloc((size_t)BH * KSPLIT * LM * DH);
    Bu.a3v  = alloc((size_t)BH * LM * DH);
    Bu.M2   = alloc((size_t)BH * LM * DH);
    Bu.scal = alloc(64);
    Bu.attn_cls = alloc(BATCH * DIM);
    Bu.h_cls    = alloc(BATCH * DIM);
    float* Kc    = alloc(49 * DIM);
    float* biasC = alloc(DIM);
    Bu.actb_h = (unsigned short*)alloc((size_t)MPAD * DIM / 2);
    Bu.actb_l = (unsigned short*)alloc((size_t)MPAD * DIM / 2);
    unsigned short* W1t_h   = (unsigned short*)alloc((size_t)DIM * INDIM / 2);
    unsigned short* W1t_l   = (unsigned short*)alloc((size_t)DIM * INDIM / 2);
    unsigned short* Wqkvt_h = (unsigned short*)alloc((size_t)DIM * 3 * DIM / 2);  // shared by both layers
    unsigned short* Wqkvt_l = (unsigned short*)alloc((size_t)DIM * 3 * DIM / 2);
    unsigned short* Wo1t_h  = (unsigned short*)alloc((size_t)DIM * DIM / 2);
    unsigned short* Wo1t_l  = (unsigned short*)alloc((size_t)DIM * DIM / 2);
    // feat hi/lo alias into S (S unused until after w1 GEMM)
    unsigned short* featb_h = (unsigned short*)Bu.S;
    unsigned short* featb_l = featb_h + (size_t)BATCH * 16384 * INDIM;

    // zero pad rows of activation buffers (rows MROWS..MPAD), once per launch
    hipMemsetAsync(Bu.actb_h + (size_t)MROWS * DIM, 0, (size_t)(MPAD - MROWS) * DIM * 2, stream);
    hipMemsetAsync(Bu.actb_l + (size_t)MROWS * DIM, 0, (size_t)(MPAD - MROWS) * DIM * 2, stream);

    // weight prep (split f16, transposed to [N][K])
    k_wt_split<<<dim3((INDIM * DIM + 255) / 256), 256, 0, stream>>>(W1, W1t_h, W1t_l, INDIM, DIM);
    k_wt_split<<<dim3((DIM * 3 * DIM + 255) / 256), 256, 0, stream>>>(Wqkv1, Wqkvt_h, Wqkvt_l, DIM, 3 * DIM);
    k_wt_split<<<dim3((DIM * DIM + 255) / 256), 256, 0, stream>>>(Wout1, Wo1t_h, Wo1t_l, DIM, DIM);
    // features -> split f16
    k_cvt_split<<<dim3((BATCH * 16384 * INDIM / 4 + 255) / 256), 256, 0, stream>>>(
        features, featb_h, featb_l, BATCH * 16384 * INDIM / 4);

    // 1) h = relu(features @ W1 + b1), prepend cls
    k_set_cls<<<dim3(4), 256, 0, stream>>>(cls, h1);
    k_w1_s<<<dim3(4, 256), 256, 0, stream>>>(featb_h, featb_l, W1t_h, W1t_l, b1, h1);
    // 2) h += nystrom_attention(LN(h))  (full)
    run_attention(stream, h1, h1, h2, ln1_g, ln1_b, Wqkvt_h, Wqkvt_l, Wo1t_h, Wo1t_l,
                  nullptr, bout1, resk1, true, Bu);
    // 3) PPEG
    k_combine<<<dim3(2, 49), 256, 0, stream>>>(k7, b7c, k5, b5c, k3, b3c, Kc, biasC);
    k_ppeg2<<<dim3(4, 4, BATCH * 64), 256, 0, stream>>>(h1, Kc, biasC, h2);
    k_copy_cls<<<dim3(4), 256, 0, stream>>>(h1, h2);
    // 4) second attention — only cls token needed downstream; reuse Wqkv staging buffer
    k_wt_split<<<dim3((DIM * 3 * DIM + 255) / 256), 256, 0, stream>>>(Wqkv2, Wqkvt_h, Wqkvt_l, DIM, 3 * DIM);
    run_attention(stream, h2, nullptr, nullptr, ln2_g, ln2_b, Wqkvt_h, Wqkvt_l, nullptr, nullptr,
                  Wout2, bout2, resk2, false, Bu);
    // 5) final LN on cls + linear head
    k_final<<<dim3(BATCH), 256, 0, stream>>>(Bu.h_cls, lnf_g, lnf_b, W2, b2, out);
}